// Round 1
// baseline (1525.423 us; speedup 1.0000x reference)
//
#include <hip/hip_runtime.h>

#define EPS_C 0.01f

// ---------- workspace layout (float offsets) ----------
// H    : 0        320*320 = 102400
// C    : 102400   256*256 (P, factored in place; row k of C = column k of L)
// CT   : 167936   256*256 (transpose of factored C)
// Y    : 233472   256*256
// RHS  : 299008   256*64
// C1T  : 315392   256*64   (C1T[d][q] = C1[q][d])
// D11  : 331776   64*64
// Wf   : 335872   256*328  ([A | B1 | B2] row-major, stride 328)
// wg   : 419840   65536*64
#define WS_H    0
#define WS_C    102400
#define WS_CT   167936
#define WS_Y    233472
#define WS_RHS  299008
#define WS_C1T  315392
#define WS_D11  331776
#define WS_WF   335872
#define WS_WG   419840

// ---------------- setup: P and H builds (fully parallel) ----------------
__global__ void k_build(const float* __restrict__ Xm, const float* __restrict__ XPm,
                        float* __restrict__ H, float* __restrict__ P) {
    int idx = blockIdx.x * 256 + threadIdx.x;
    if (idx < 102400) {
        int i = idx / 320, j = idx - i * 320;
        const float4* a = (const float4*)(Xm + i * 320);
        const float4* b = (const float4*)(Xm + j * 320);
        float s = 0.f;
        for (int k = 0; k < 80; ++k) {
            float4 va = a[k], vb = b[k];
            s += va.x * vb.x + va.y * vb.y + va.z * vb.z + va.w * vb.w;
        }
        H[idx] = (i == j) ? s + EPS_C : s;
    } else {
        idx -= 102400;
        if (idx < 65536) {
            int i = idx >> 8, j = idx & 255;
            const float4* a = (const float4*)(XPm + i * 256);
            const float4* b = (const float4*)(XPm + j * 256);
            float s = 0.f;
            for (int k = 0; k < 64; ++k) {
                float4 va = a[k], vb = b[k];
                s += va.x * vb.x + va.y * vb.y + va.z * vb.z + va.w * vb.w;
            }
            P[idx] = (i == j) ? s + EPS_C : s;
        }
    }
}

// ---------------- setup: derived small matrices (elementwise) ----------------
__global__ void k_derived(const float* __restrict__ H, const float* __restrict__ Um,
                          const float* __restrict__ Y1, const float* __restrict__ B2,
                          float* __restrict__ Y, float* __restrict__ RHS,
                          float* __restrict__ C1T, float* __restrict__ D11g,
                          float* __restrict__ Wf) {
    int idx = blockIdx.x * 256 + threadIdx.x;
    if (idx < 65536) {
        int i = idx >> 8, j = idx & 255;
        Y[idx] = -0.5f * (H[i * 320 + j] + Y1[i * 256 + j] - Y1[j * 256 + i]);
        return;
    }
    idx -= 65536;
    if (idx < 16384) { // RHS = -H12 - U
        int d = idx >> 6, q = idx & 63;
        RHS[idx] = -H[d * 320 + 256 + q] - Um[idx];
        return;
    }
    idx -= 16384;
    if (idx < 16384) { // C1T[d][q] = U[d][q]/lam[q]
        int q = idx & 63;
        float lam = 0.5f * H[(256 + q) * 320 + 256 + q];
        C1T[idx] = Um[idx] / lam;
        return;
    }
    idx -= 16384;
    if (idx < 4096) { // D11[q][j] = (j<q) ? -H22[q][j]/lam[q] : 0
        int q = idx >> 6, j = idx & 63;
        float lam = 0.5f * H[(256 + q) * 320 + 256 + q];
        D11g[idx] = (j < q) ? -H[(256 + q) * 320 + 256 + j] / lam : 0.f;
        return;
    }
    idx -= 4096;
    if (idx < 2048) { // Wf tail: B2
        int o = idx >> 3, k = idx & 7;
        Wf[(size_t)o * 328 + 320 + k] = B2[idx];
    }
}

// ---------------- setup: single-block blocked Cholesky ----------------
// Storage convention: C[k*256+i] = L[i][k]  (row k of C = column k of L).
// Init C = P (symmetric) works directly. All global accesses row-contiguous.
__global__ void __launch_bounds__(256) k_chol(float* __restrict__ C) {
    __shared__ __align__(16) float pan[64 * 256]; // pan[c][i]: column k0+c of L
    const int tid = threadIdx.x;
    const int il = tid & 63, cs = tid >> 6;  // panel phases
    const int ig = tid & 15, jg = tid >> 4;  // trailing phases (16x16)
    for (int s = 0; s < 4; ++s) {
        const int k0 = s * 64;
        // load panel (cols k0..k0+63, entries i >= k0)
        for (int c = cs; c < 64; c += 4)
            for (int i = k0 + il; i < 256; i += 64)
                pan[c * 256 + i] = C[(k0 + c) * 256 + i];
        __syncthreads();
        // factor panel in LDS
        for (int kk = 0; kk < 64; ++kk) {
            const int k = k0 + kk;
            const float dval = sqrtf(pan[kk * 256 + k]); // all threads read (broadcast)
            __syncthreads();
            const float inv = 1.f / dval;
            {
                const int i = k0 + tid;
                if (i < 256 && i >= k) {
                    float v = pan[kk * 256 + i] * inv;
                    if (i == k) v = dval;
                    pan[kk * 256 + i] = v;
                }
            }
            __syncthreads();
            for (int c = kk + 1 + cs; c < 64; c += 4) {
                const float f = pan[kk * 256 + k0 + c];
                for (int i = k0 + il; i < 256; i += 64)
                    pan[c * 256 + i] -= pan[kk * 256 + i] * f;
            }
            __syncthreads();
        }
        // store panel back
        for (int c = cs; c < 64; c += 4)
            for (int i = k0 + il; i < 256; i += 64)
                C[(k0 + c) * 256 + i] = pan[c * 256 + i];
        __syncthreads();
        // trailing update: C[j][i] -= sum_c pan[c][i]*pan[c][j], j,i >= k1
        const int k1 = k0 + 64;
        const int nrem = 256 - k1;
        if (nrem > 0) {
            const int nt = nrem >> 2;
            for (int jt = jg; jt < nt; jt += 16)
                for (int it = ig; it < nt; it += 16) {
                    if (it < jt) continue;
                    const int j0 = k1 + jt * 4, i0 = k1 + it * 4;
                    float4 a0 = *(float4*)&C[(j0 + 0) * 256 + i0];
                    float4 a1 = *(float4*)&C[(j0 + 1) * 256 + i0];
                    float4 a2 = *(float4*)&C[(j0 + 2) * 256 + i0];
                    float4 a3 = *(float4*)&C[(j0 + 3) * 256 + i0];
                    for (int c = 0; c < 64; ++c) {
                        const float4 pi = *(const float4*)&pan[c * 256 + i0];
                        const float p0 = pan[c * 256 + j0 + 0];
                        const float p1 = pan[c * 256 + j0 + 1];
                        const float p2 = pan[c * 256 + j0 + 2];
                        const float p3 = pan[c * 256 + j0 + 3];
                        a0.x -= pi.x * p0; a0.y -= pi.y * p0; a0.z -= pi.z * p0; a0.w -= pi.w * p0;
                        a1.x -= pi.x * p1; a1.y -= pi.y * p1; a1.z -= pi.z * p1; a1.w -= pi.w * p1;
                        a2.x -= pi.x * p2; a2.y -= pi.y * p2; a2.z -= pi.z * p2; a2.w -= pi.w * p2;
                        a3.x -= pi.x * p3; a3.y -= pi.y * p3; a3.z -= pi.z * p3; a3.w -= pi.w * p3;
                    }
                    *(float4*)&C[(j0 + 0) * 256 + i0] = a0;
                    *(float4*)&C[(j0 + 1) * 256 + i0] = a1;
                    *(float4*)&C[(j0 + 2) * 256 + i0] = a2;
                    *(float4*)&C[(j0 + 3) * 256 + i0] = a3;
                }
        }
        __syncthreads();
    }
}

__global__ void k_transp(const float* __restrict__ C, float* __restrict__ CT) {
    int idx = blockIdx.x * 256 + threadIdx.x; // 65536
    int i = idx >> 8, k = idx & 255;
    CT[idx] = C[k * 256 + i];
}

// ---------------- setup: triangular solves, 4 columns per 1-wave block ----------------
// Solves P z = b for b = columns of [Y | RHS]; writes result into Wf[:, cc].
__global__ void __launch_bounds__(64) k_solve(const float* __restrict__ C, const float* __restrict__ CT,
                                              const float* __restrict__ Y, const float* __restrict__ RHS,
                                              float* __restrict__ Wf) {
    __shared__ float z[256 * 5];
    const int il = threadIdx.x;
    const int cc0 = blockIdx.x * 4;
    for (int m = 0; m < 4; ++m) {
        const int i = il + 64 * m;
        for (int c = 0; c < 4; ++c) {
            const int cc = cc0 + c;
            z[i * 5 + c] = (cc < 256) ? Y[i * 256 + cc] : RHS[i * 64 + (cc - 256)];
        }
    }
    __syncthreads();
    // forward: L v = b        (L[i][k] = C[k*256+i])
    for (int k = 0; k < 256; ++k) {
        const float d = C[k * 256 + k];
        float zk[4];
#pragma unroll
        for (int c = 0; c < 4; ++c) zk[c] = z[k * 5 + c] / d; // all lanes read old value (wave in-order), then:
        if (il == 0) {
#pragma unroll
            for (int c = 0; c < 4; ++c) z[k * 5 + c] = zk[c];
        }
        for (int i = k + 1 + il; i < 256; i += 64) {
            const float f = C[k * 256 + i];
#pragma unroll
            for (int c = 0; c < 4; ++c) z[i * 5 + c] -= f * zk[c];
        }
        __syncthreads();
    }
    // backward: L^T a = v     (L^T[i][k] = L[k][i] = C[i*256+k] = CT[k*256+i])
    for (int k = 255; k >= 0; --k) {
        const float d = C[k * 256 + k];
        float zk[4];
#pragma unroll
        for (int c = 0; c < 4; ++c) zk[c] = z[k * 5 + c] / d;
        if (il == 0) {
#pragma unroll
            for (int c = 0; c < 4; ++c) z[k * 5 + c] = zk[c];
        }
        for (int i = il; i < k; i += 64) {
            const float f = CT[k * 256 + i];
#pragma unroll
            for (int c = 0; c < 4; ++c) z[i * 5 + c] -= f * zk[c];
        }
        __syncthreads();
    }
    for (int m = 0; m < 4; ++m) {
        const int i = il + 64 * m;
        for (int c = 0; c < 4; ++c) Wf[(size_t)i * 328 + cc0 + c] = z[i * 5 + c];
    }
}

// ---------------- main 1: base + recurrence -> w ----------------
#define M1_ROWS 32
__global__ void __launch_bounds__(256) k_m1(const float* __restrict__ x, const float* __restrict__ u,
                                            const float* __restrict__ C1T, const float* __restrict__ D12,
                                            const float* __restrict__ bv, const float* __restrict__ D11g,
                                            float* __restrict__ wg) {
    __shared__ __align__(16) float xs[M1_ROWS * 256];
    __shared__ float us[M1_ROWS * 8];
    __shared__ float base_s[M1_ROWS * 66];
    __shared__ __align__(16) float w_s[M1_ROWS * 68];
    const int tid = threadIdx.x;
    const int r0 = blockIdx.x * M1_ROWS;
    {
        const float4* x4 = (const float4*)(x + (size_t)r0 * 256);
        float4* xs4 = (float4*)xs;
        for (int e = tid; e < M1_ROWS * 64; e += 256) xs4[e] = x4[e];
        for (int e = tid; e < M1_ROWS * 8; e += 256) us[e] = u[(size_t)r0 * 8 + e];
    }
    __syncthreads();
    // base[r][q] = sum_d x[r][d]*C1T[d][q] + sum_k u[r][k]*D12[q][k] + bv[q]
    {
        const int q = tid & 63, rg = tid >> 6;
        float acc[8];
#pragma unroll
        for (int rr = 0; rr < 8; ++rr) acc[rr] = 0.f;
        for (int d4 = 0; d4 < 64; ++d4) {
            const float c0 = C1T[(d4 * 4 + 0) * 64 + q];
            const float c1 = C1T[(d4 * 4 + 1) * 64 + q];
            const float c2 = C1T[(d4 * 4 + 2) * 64 + q];
            const float c3 = C1T[(d4 * 4 + 3) * 64 + q];
#pragma unroll
            for (int rr = 0; rr < 8; ++rr) {
                const int r = rg * 8 + rr;
                const float4 xv = *(const float4*)&xs[r * 256 + d4 * 4];
                acc[rr] += xv.x * c0 + xv.y * c1 + xv.z * c2 + xv.w * c3;
            }
        }
        const float bq = bv[q];
#pragma unroll
        for (int rr = 0; rr < 8; ++rr) {
            const int r = rg * 8 + rr;
            float s = acc[rr] + bq;
#pragma unroll
            for (int k = 0; k < 8; ++k) s += us[r * 8 + k] * D12[q * 8 + k];
            base_s[r * 66 + q] = s;
        }
    }
    __syncthreads();
    // recurrence: w[i] = relu(base[i] + sum_{j<i} w[j]*D11[i][j]); 8 lanes per row
    {
        const int p = tid & 7, r = tid >> 3;
        float* wrow = w_s + r * 68;
        const float* brow = base_s + r * 66;
        for (int i = 0; i < 64; ++i) {
            float s = 0.f;
            for (int j = p; j < i; j += 8) s += wrow[j] * D11g[i * 64 + j];
            s += __shfl_xor(s, 1);
            s += __shfl_xor(s, 2);
            s += __shfl_xor(s, 4);
            if (p == 0) {
                const float wi = brow[i] + s;
                wrow[i] = wi > 0.f ? wi : 0.f;
            }
            __syncthreads();
        }
    }
    {
        float4* wg4 = (float4*)(wg + (size_t)r0 * 64);
        for (int e = tid; e < M1_ROWS * 16; e += 256) {
            const int r = e >> 4, q4 = e & 15;
            wg4[e] = *(const float4*)&w_s[r * 68 + q4 * 4];
        }
    }
}

// ---------------- main 2: out = [x|w|u] @ Wf^T ----------------
#define M2_ROWS 32
__global__ void __launch_bounds__(256) k_m2(const float* __restrict__ x, const float* __restrict__ wg,
                                            const float* __restrict__ u, const float* __restrict__ Wf,
                                            float* __restrict__ out) {
    __shared__ __align__(16) float ins[M2_ROWS * 328];
    const int tid = threadIdx.x;
    const int r0 = blockIdx.x * M2_ROWS;
    {
        const float4* x4 = (const float4*)(x + (size_t)r0 * 256);
        const float4* w4 = (const float4*)(wg + (size_t)r0 * 64);
        const float4* u4 = (const float4*)(u + (size_t)r0 * 8);
        for (int e = tid; e < M2_ROWS * 64; e += 256) {
            const int r = e >> 6, c4 = e & 63;
            *(float4*)&ins[r * 328 + c4 * 4] = x4[e];
        }
        for (int e = tid; e < M2_ROWS * 16; e += 256) {
            const int r = e >> 4, c4 = e & 15;
            *(float4*)&ins[r * 328 + 256 + c4 * 4] = w4[e];
        }
        for (int e = tid; e < M2_ROWS * 2; e += 256) {
            const int r = e >> 1, c4 = e & 1;
            *(float4*)&ins[r * 328 + 320 + c4 * 4] = u4[e];
        }
    }
    __syncthreads();
    const int to = tid & 31, tr = tid >> 5;
    float acc[8][4];
#pragma unroll
    for (int m = 0; m < 8; ++m)
#pragma unroll
        for (int rr = 0; rr < 4; ++rr) acc[m][rr] = 0.f;
    for (int c4 = 0; c4 < 82; ++c4) {
        float4 xv[4];
#pragma unroll
        for (int rr = 0; rr < 4; ++rr) xv[rr] = *(const float4*)&ins[(tr * 4 + rr) * 328 + c4 * 4];
#pragma unroll
        for (int m = 0; m < 8; ++m) {
            const float4 wv = *(const float4*)&Wf[(size_t)(to + 32 * m) * 328 + c4 * 4];
#pragma unroll
            for (int rr = 0; rr < 4; ++rr)
                acc[m][rr] += wv.x * xv[rr].x + wv.y * xv[rr].y + wv.z * xv[rr].z + wv.w * xv[rr].w;
        }
    }
#pragma unroll
    for (int m = 0; m < 8; ++m)
#pragma unroll
        for (int rr = 0; rr < 4; ++rr)
            out[(size_t)(r0 + tr * 4 + rr) * 256 + to + 32 * m] = acc[m][rr];
}

extern "C" void kernel_launch(void* const* d_in, const int* in_sizes, int n_in,
                              void* d_out, int out_size, void* d_ws, size_t ws_size,
                              hipStream_t stream) {
    const float* x   = (const float*)d_in[0];
    const float* u   = (const float*)d_in[1];
    const float* Xm  = (const float*)d_in[2];
    const float* Um  = (const float*)d_in[3];
    const float* Y1  = (const float*)d_in[4];
    const float* XPm = (const float*)d_in[5];
    const float* B2  = (const float*)d_in[6];
    const float* D12 = (const float*)d_in[7];
    const float* bv  = (const float*)d_in[8];
    float* out = (float*)d_out;
    float* ws  = (float*)d_ws;

    float* H    = ws + WS_H;
    float* C    = ws + WS_C;
    float* CT   = ws + WS_CT;
    float* Y    = ws + WS_Y;
    float* RHS  = ws + WS_RHS;
    float* C1T  = ws + WS_C1T;
    float* D11g = ws + WS_D11;
    float* Wf   = ws + WS_WF;
    float* wg   = ws + WS_WG;

    k_build<<<656, 256, 0, stream>>>(Xm, XPm, H, C);
    k_derived<<<408, 256, 0, stream>>>(H, Um, Y1, B2, Y, RHS, C1T, D11g, Wf);
    k_chol<<<1, 256, 0, stream>>>(C);
    k_transp<<<256, 256, 0, stream>>>(C, CT);
    k_solve<<<80, 64, 0, stream>>>(C, CT, Y, RHS, Wf);
    k_m1<<<2048, 256, 0, stream>>>(x, u, C1T, D12, bv, D11g, wg);
    k_m2<<<2048, 256, 0, stream>>>(x, wg, u, Wf, out);
}

// Round 3
// 1034.211 us; speedup vs baseline: 1.4750x; 1.4750x over previous
//
#include <hip/hip_runtime.h>

#define EPS_C 0.01f

typedef __attribute__((ext_vector_type(8))) short short8;
typedef __attribute__((ext_vector_type(4))) float f32x4;
typedef __attribute__((ext_vector_type(4))) unsigned short u16x4;
typedef __attribute__((ext_vector_type(8))) unsigned short u16x8;

// ---------- workspace layout (float offsets) ----------
#define WS_H    0        // 320*320
#define WS_C    102400   // 256*256
#define WS_CT   167936   // 256*256
#define WS_Y    233472   // 256*256
#define WS_RHS  299008   // 256*64
#define WS_C1T  315392   // 256*64
#define WS_D11  331776   // 64*64
#define WS_WF   335872   // 256*328 fp32
#define WS_WFH  419840   // 256*352 u16 = 45056 floats
#define WS_WFM  464896
#define WS_WFL  509952
#define WS_WG   555008   // 65536*64 fp32 -> ends 4749312 floats (~19 MB)

__device__ __forceinline__ unsigned short f2bf(float f) {
    unsigned int u = __float_as_uint(f);
    unsigned int r = (u + 0x7fffu + ((u >> 16) & 1u)) >> 16;
    return (unsigned short)r;
}
__device__ __forceinline__ float bf2f(unsigned short h) {
    return __uint_as_float(((unsigned int)h) << 16);
}

// ---------------- setup: P and H builds ----------------
__global__ void k_build(const float* __restrict__ Xm, const float* __restrict__ XPm,
                        float* __restrict__ H, float* __restrict__ P) {
    int idx = blockIdx.x * 256 + threadIdx.x;
    if (idx < 102400) {
        int i = idx / 320, j = idx - i * 320;
        const float4* a = (const float4*)(Xm + i * 320);
        const float4* b = (const float4*)(Xm + j * 320);
        float s = 0.f;
        for (int k = 0; k < 80; ++k) {
            float4 va = a[k], vb = b[k];
            s += va.x * vb.x + va.y * vb.y + va.z * vb.z + va.w * vb.w;
        }
        H[idx] = (i == j) ? s + EPS_C : s;
    } else {
        idx -= 102400;
        if (idx < 65536) {
            int i = idx >> 8, j = idx & 255;
            const float4* a = (const float4*)(XPm + i * 256);
            const float4* b = (const float4*)(XPm + j * 256);
            float s = 0.f;
            for (int k = 0; k < 64; ++k) {
                float4 va = a[k], vb = b[k];
                s += va.x * vb.x + va.y * vb.y + va.z * vb.z + va.w * vb.w;
            }
            P[idx] = (i == j) ? s + EPS_C : s;
        }
    }
}

// ---------------- setup: derived small matrices ----------------
__global__ void k_derived(const float* __restrict__ H, const float* __restrict__ Um,
                          const float* __restrict__ Y1, const float* __restrict__ B2,
                          float* __restrict__ Y, float* __restrict__ RHS,
                          float* __restrict__ C1T, float* __restrict__ D11g,
                          float* __restrict__ Wf) {
    int idx = blockIdx.x * 256 + threadIdx.x;
    if (idx < 65536) {
        int i = idx >> 8, j = idx & 255;
        Y[idx] = -0.5f * (H[i * 320 + j] + Y1[i * 256 + j] - Y1[j * 256 + i]);
        return;
    }
    idx -= 65536;
    if (idx < 16384) { // RHS = -H12 - U
        RHS[idx] = -H[(idx >> 6) * 320 + 256 + (idx & 63)] - Um[idx];
        return;
    }
    idx -= 16384;
    if (idx < 16384) { // C1T[d][q] = U[d][q]/lam[q]
        int q = idx & 63;
        float lam = 0.5f * H[(256 + q) * 320 + 256 + q];
        C1T[idx] = Um[idx] / lam;
        return;
    }
    idx -= 16384;
    if (idx < 4096) { // D11[q][j]
        int q = idx >> 6, j = idx & 63;
        float lam = 0.5f * H[(256 + q) * 320 + 256 + q];
        D11g[idx] = (j < q) ? -H[(256 + q) * 320 + 256 + j] / lam : 0.f;
        return;
    }
    idx -= 4096;
    if (idx < 2048) { // Wf tail: B2 at cols 320..327
        int o = idx >> 3, k = idx & 7;
        Wf[(size_t)o * 328 + 320 + k] = B2[idx];
    }
}

// ---------------- setup: single-block blocked Cholesky ----------------
__global__ void __launch_bounds__(256) k_chol(float* __restrict__ C) {
    __shared__ __align__(16) float pan[64 * 256];
    const int tid = threadIdx.x;
    const int il = tid & 63, cs = tid >> 6;
    const int ig = tid & 15, jg = tid >> 4;
    for (int s = 0; s < 4; ++s) {
        const int k0 = s * 64;
        for (int c = cs; c < 64; c += 4)
            for (int i = k0 + il; i < 256; i += 64)
                pan[c * 256 + i] = C[(k0 + c) * 256 + i];
        __syncthreads();
        for (int kk = 0; kk < 64; ++kk) {
            const int k = k0 + kk;
            const float dval = sqrtf(pan[kk * 256 + k]);
            __syncthreads();
            const float inv = 1.f / dval;
            {
                const int i = k0 + tid;
                if (i < 256 && i >= k) {
                    float v = pan[kk * 256 + i] * inv;
                    if (i == k) v = dval;
                    pan[kk * 256 + i] = v;
                }
            }
            __syncthreads();
            for (int c = kk + 1 + cs; c < 64; c += 4) {
                const float f = pan[kk * 256 + k0 + c];
                for (int i = k0 + il; i < 256; i += 64)
                    pan[c * 256 + i] -= pan[kk * 256 + i] * f;
            }
            __syncthreads();
        }
        for (int c = cs; c < 64; c += 4)
            for (int i = k0 + il; i < 256; i += 64)
                C[(k0 + c) * 256 + i] = pan[c * 256 + i];
        __syncthreads();
        const int k1 = k0 + 64;
        const int nrem = 256 - k1;
        if (nrem > 0) {
            const int nt = nrem >> 2;
            for (int jt = jg; jt < nt; jt += 16)
                for (int it = ig; it < nt; it += 16) {
                    if (it < jt) continue;
                    const int j0 = k1 + jt * 4, i0 = k1 + it * 4;
                    float4 a0 = *(float4*)&C[(j0 + 0) * 256 + i0];
                    float4 a1 = *(float4*)&C[(j0 + 1) * 256 + i0];
                    float4 a2 = *(float4*)&C[(j0 + 2) * 256 + i0];
                    float4 a3 = *(float4*)&C[(j0 + 3) * 256 + i0];
                    for (int c = 0; c < 64; ++c) {
                        const float4 pi = *(const float4*)&pan[c * 256 + i0];
                        const float p0 = pan[c * 256 + j0 + 0];
                        const float p1 = pan[c * 256 + j0 + 1];
                        const float p2 = pan[c * 256 + j0 + 2];
                        const float p3 = pan[c * 256 + j0 + 3];
                        a0.x -= pi.x * p0; a0.y -= pi.y * p0; a0.z -= pi.z * p0; a0.w -= pi.w * p0;
                        a1.x -= pi.x * p1; a1.y -= pi.y * p1; a1.z -= pi.z * p1; a1.w -= pi.w * p1;
                        a2.x -= pi.x * p2; a2.y -= pi.y * p2; a2.z -= pi.z * p2; a2.w -= pi.w * p2;
                        a3.x -= pi.x * p3; a3.y -= pi.y * p3; a3.z -= pi.z * p3; a3.w -= pi.w * p3;
                    }
                    *(float4*)&C[(j0 + 0) * 256 + i0] = a0;
                    *(float4*)&C[(j0 + 1) * 256 + i0] = a1;
                    *(float4*)&C[(j0 + 2) * 256 + i0] = a2;
                    *(float4*)&C[(j0 + 3) * 256 + i0] = a3;
                }
        }
        __syncthreads();
    }
}

__global__ void k_transp(const float* __restrict__ C, float* __restrict__ CT) {
    int idx = blockIdx.x * 256 + threadIdx.x;
    int i = idx >> 8, k = idx & 255;
    CT[idx] = C[k * 256 + i];
}

// ---------------- setup: triangular solves ----------------
__global__ void __launch_bounds__(64) k_solve(const float* __restrict__ C, const float* __restrict__ CT,
                                              const float* __restrict__ Y, const float* __restrict__ RHS,
                                              float* __restrict__ Wf) {
    __shared__ float z[256 * 5];
    const int il = threadIdx.x;
    const int cc0 = blockIdx.x * 4;
    for (int m = 0; m < 4; ++m) {
        const int i = il + 64 * m;
        for (int c = 0; c < 4; ++c) {
            const int cc = cc0 + c;
            z[i * 5 + c] = (cc < 256) ? Y[i * 256 + cc] : RHS[i * 64 + (cc - 256)];
        }
    }
    __syncthreads();
    for (int k = 0; k < 256; ++k) {
        const float d = C[k * 256 + k];
        float zk[4];
#pragma unroll
        for (int c = 0; c < 4; ++c) zk[c] = z[k * 5 + c] / d;
        if (il == 0) {
#pragma unroll
            for (int c = 0; c < 4; ++c) z[k * 5 + c] = zk[c];
        }
        for (int i = k + 1 + il; i < 256; i += 64) {
            const float f = C[k * 256 + i];
#pragma unroll
            for (int c = 0; c < 4; ++c) z[i * 5 + c] -= f * zk[c];
        }
        __syncthreads();
    }
    for (int k = 255; k >= 0; --k) {
        const float d = C[k * 256 + k];
        float zk[4];
#pragma unroll
        for (int c = 0; c < 4; ++c) zk[c] = z[k * 5 + c] / d;
        if (il == 0) {
#pragma unroll
            for (int c = 0; c < 4; ++c) z[k * 5 + c] = zk[c];
        }
        for (int i = il; i < k; i += 64) {
            const float f = CT[k * 256 + i];
#pragma unroll
            for (int c = 0; c < 4; ++c) z[i * 5 + c] -= f * zk[c];
        }
        __syncthreads();
    }
    for (int m = 0; m < 4; ++m) {
        const int i = il + 64 * m;
        for (int c = 0; c < 4; ++c) Wf[(size_t)i * 328 + cc0 + c] = z[i * 5 + c];
    }
}

// ---------------- pack Wf -> 3-way bf16 split, layout [A | B2 | 0 | B1], K=352 ----------------
__global__ void k_packWf3(const float* __restrict__ Wf, unsigned short* __restrict__ Bh,
                          unsigned short* __restrict__ Bm, unsigned short* __restrict__ Bl) {
    int idx = blockIdx.x * 256 + threadIdx.x; // 256*352 = 90112
    if (idx >= 90112) return;
    int n = idx / 352, k = idx - n * 352;
    float f;
    if (k < 256)      f = Wf[(size_t)n * 328 + k];           // A
    else if (k < 264) f = Wf[(size_t)n * 328 + 320 + (k - 256)]; // B2
    else if (k < 288) f = 0.f;                                // pad
    else              f = Wf[(size_t)n * 328 + 256 + (k - 288)]; // B1
    unsigned short h = f2bf(f);
    float r1 = f - bf2f(h);
    unsigned short m = f2bf(r1);
    float r2 = r1 - bf2f(m);
    unsigned short l = f2bf(r2);
    Bh[idx] = h; Bm[idx] = m; Bl[idx] = l;
}

// ---------------- main 1: base + recurrence -> w (fp32) ----------------
__global__ void __launch_bounds__(256) k_m1(const float* __restrict__ x, const float* __restrict__ u,
                                            const float* __restrict__ C1T, const float* __restrict__ D12,
                                            const float* __restrict__ bv, const float* __restrict__ D11g,
                                            float* __restrict__ wg) {
    __shared__ __align__(16) float sbuf[32 * 257]; // x chunk, k-major
    __shared__ float us[256 * 9];
    const int tid = threadIdx.x;
    const int r0 = blockIdx.x * 256;
#pragma unroll
    for (int i = 0; i < 8; ++i) {
        int e = tid + i * 256, r = e >> 3, j = e & 7;
        us[r * 9 + j] = u[(size_t)(r0 + r) * 8 + j];
    }
    float w[64];
#pragma unroll
    for (int q = 0; q < 64; ++q) w[q] = bv[q];
    const float4* xg4 = (const float4*)x;
    for (int kc = 0; kc < 8; ++kc) {
        __syncthreads();
#pragma unroll
        for (int i = 0; i < 8; ++i) {
            int e = tid + i * 256, r = e >> 3, c4 = e & 7;
            float4 v = xg4[(size_t)(r0 + r) * 64 + kc * 8 + c4];
            sbuf[(c4 * 4 + 0) * 257 + r] = v.x;
            sbuf[(c4 * 4 + 1) * 257 + r] = v.y;
            sbuf[(c4 * 4 + 2) * 257 + r] = v.z;
            sbuf[(c4 * 4 + 3) * 257 + r] = v.w;
        }
        __syncthreads();
        const float* c1p = C1T + kc * 32 * 64;
#pragma unroll 4
        for (int k = 0; k < 32; ++k) {
            float xv = sbuf[k * 257 + tid];
#pragma unroll
            for (int q = 0; q < 64; ++q) w[q] = fmaf(xv, c1p[k * 64 + q], w[q]);
        }
    }
#pragma unroll
    for (int j = 0; j < 8; ++j) {
        float uv = us[tid * 9 + j];
#pragma unroll
        for (int q = 0; q < 64; ++q) w[q] = fmaf(uv, D12[q * 8 + j], w[q]);
    }
    // recurrence, fully in registers (static indexing)
    w[0] = fmaxf(w[0], 0.f);
#pragma unroll
    for (int i = 1; i < 64; ++i) {
        float s = w[i];
#pragma unroll
        for (int j = 0; j < i; ++j) s = fmaf(w[j], D11g[i * 64 + j], s);
        w[i] = fmaxf(s, 0.f);
    }
    // direct fp32 store (per-thread row, float4)
    float* wr = wg + (size_t)(r0 + tid) * 64;
#pragma unroll
    for (int c = 0; c < 16; ++c) {
        float4 v = {w[4 * c], w[4 * c + 1], w[4 * c + 2], w[4 * c + 3]};
        *(float4*)&wr[c * 4] = v;
    }
}

// ---------------- main 2: out = [x|u|0|w] @ WfP^T via tiered bf16x3-split MFMA ----------------
#define ASTR 360
__global__ void __launch_bounds__(256) k_m2(const float* __restrict__ x, const float* __restrict__ wg,
                                            const float* __restrict__ u,
                                            const unsigned short* __restrict__ Bh,
                                            const unsigned short* __restrict__ Bm,
                                            const unsigned short* __restrict__ Bl,
                                            float* __restrict__ out) {
    __shared__ __align__(16) unsigned short Ah[32 * ASTR];
    __shared__ __align__(16) unsigned short Am[32 * ASTR];
    __shared__ __align__(16) unsigned short Al[32 * ASTR];
    const int tid = threadIdx.x;
    const int r0 = blockIdx.x * 32;
    // stage x -> cols 0..255 (3-way split)
    {
        const float4* xg4 = (const float4*)(x + (size_t)r0 * 256);
#pragma unroll
        for (int i = 0; i < 8; ++i) {
            int e = tid + i * 256, r = e >> 6, c4 = e & 63;
            float4 v = xg4[e];
            float vv[4] = {v.x, v.y, v.z, v.w};
            u16x4 hv, mv, lv;
#pragma unroll
            for (int j = 0; j < 4; ++j) {
                unsigned short h = f2bf(vv[j]);
                float rr1 = vv[j] - bf2f(h);
                unsigned short m = f2bf(rr1);
                lv[j] = f2bf(rr1 - bf2f(m));
                hv[j] = h; mv[j] = m;
            }
            *(u16x4*)&Ah[r * ASTR + c4 * 4] = hv;
            *(u16x4*)&Am[r * ASTR + c4 * 4] = mv;
            *(u16x4*)&Al[r * ASTR + c4 * 4] = lv;
        }
    }
    // stage u -> cols 256..263
    if (tid < 64) {
        int r = tid >> 1, h4 = tid & 1;
        float4 v = *(const float4*)&u[(size_t)(r0 + r) * 8 + h4 * 4];
        float vv[4] = {v.x, v.y, v.z, v.w};
        u16x4 hv, mv, lv;
#pragma unroll
        for (int j = 0; j < 4; ++j) {
            unsigned short h = f2bf(vv[j]);
            float rr1 = vv[j] - bf2f(h);
            unsigned short m = f2bf(rr1);
            lv[j] = f2bf(rr1 - bf2f(m));
            hv[j] = h; mv[j] = m;
        }
        *(u16x4*)&Ah[r * ASTR + 256 + h4 * 4] = hv;
        *(u16x4*)&Am[r * ASTR + 256 + h4 * 4] = mv;
        *(u16x4*)&Al[r * ASTR + 256 + h4 * 4] = lv;
    }
    // zero pad cols 264..287
    if (tid < 96) {
        int r = tid / 3, c = tid - r * 3;
        u16x8 z = {0, 0, 0, 0, 0, 0, 0, 0};
        *(u16x8*)&Ah[r * ASTR + 264 + c * 8] = z;
        *(u16x8*)&Am[r * ASTR + 264 + c * 8] = z;
        *(u16x8*)&Al[r * ASTR + 264 + c * 8] = z;
    }
    // stage w -> cols 288..351 (3-way split)
    {
        int r = tid >> 3, c8 = tid & 7;
        const float4* wp = (const float4*)&wg[(size_t)(r0 + r) * 64 + c8 * 8];
        float4 v0 = wp[0], v1 = wp[1];
        float vv[8] = {v0.x, v0.y, v0.z, v0.w, v1.x, v1.y, v1.z, v1.w};
        u16x8 hv, mv, lv;
#pragma unroll
        for (int j = 0; j < 8; ++j) {
            unsigned short h = f2bf(vv[j]);
            float rr1 = vv[j] - bf2f(h);
            unsigned short m = f2bf(rr1);
            lv[j] = f2bf(rr1 - bf2f(m));
            hv[j] = h; mv[j] = m;
        }
        *(u16x8*)&Ah[r * ASTR + 288 + c8 * 8] = hv;
        *(u16x8*)&Am[r * ASTR + 288 + c8 * 8] = mv;
        *(u16x8*)&Al[r * ASTR + 288 + c8 * 8] = lv;
    }
    __syncthreads();

    const int lane = tid & 63, wid = tid >> 6;
    const int n0 = wid * 64;
    const int lr = lane & 15, lg = lane >> 4;
    const int lk = lg * 8;
    f32x4 acc[2][4];
#pragma unroll
    for (int m = 0; m < 2; ++m)
#pragma unroll
        for (int nf = 0; nf < 4; ++nf) acc[m][nf] = (f32x4){0.f, 0.f, 0.f, 0.f};

    for (int kt = 0; kt < 11; ++kt) {
        const int ka = kt * 32 + lk;
        short8 a_h[2], a_m[2], a_l[2];
        a_h[0] = *(const short8*)&Ah[lr * ASTR + ka];
        a_h[1] = *(const short8*)&Ah[(16 + lr) * ASTR + ka];
        a_m[0] = *(const short8*)&Am[lr * ASTR + ka];
        a_m[1] = *(const short8*)&Am[(16 + lr) * ASTR + ka];
        a_l[0] = *(const short8*)&Al[lr * ASTR + ka];
        a_l[1] = *(const short8*)&Al[(16 + lr) * ASTR + ka];
        short8 b_h[4], b_m[4], b_l[4];
#pragma unroll
        for (int nf = 0; nf < 4; ++nf) {
            const size_t n = (size_t)(n0 + nf * 16 + lr);
            b_h[nf] = *(const short8*)&Bh[n * 352 + ka];
            b_m[nf] = *(const short8*)&Bm[n * 352 + ka];
            b_l[nf] = *(const short8*)&Bl[n * 352 + ka];
        }
        const bool wtile = (kt >= 9);
#pragma unroll
        for (int m = 0; m < 2; ++m)
#pragma unroll
            for (int nf = 0; nf < 4; ++nf) {
                acc[m][nf] = __builtin_amdgcn_mfma_f32_16x16x32_bf16(a_h[m], b_h[nf], acc[m][nf], 0, 0, 0);
                acc[m][nf] = __builtin_amdgcn_mfma_f32_16x16x32_bf16(a_m[m], b_h[nf], acc[m][nf], 0, 0, 0);
                acc[m][nf] = __builtin_amdgcn_mfma_f32_16x16x32_bf16(a_h[m], b_m[nf], acc[m][nf], 0, 0, 0);
                acc[m][nf] = __builtin_amdgcn_mfma_f32_16x16x32_bf16(a_l[m], b_h[nf], acc[m][nf], 0, 0, 0);
                acc[m][nf] = __builtin_amdgcn_mfma_f32_16x16x32_bf16(a_m[m], b_m[nf], acc[m][nf], 0, 0, 0);
                acc[m][nf] = __builtin_amdgcn_mfma_f32_16x16x32_bf16(a_h[m], b_l[nf], acc[m][nf], 0, 0, 0);
                if (wtile) {
                    acc[m][nf] = __builtin_amdgcn_mfma_f32_16x16x32_bf16(a_m[m], b_l[nf], acc[m][nf], 0, 0, 0);
                    acc[m][nf] = __builtin_amdgcn_mfma_f32_16x16x32_bf16(a_l[m], b_m[nf], acc[m][nf], 0, 0, 0);
                }
            }
    }
#pragma unroll
    for (int m = 0; m < 2; ++m)
#pragma unroll
        for (int nf = 0; nf < 4; ++nf)
#pragma unroll
            for (int j = 0; j < 4; ++j)
                out[(size_t)(r0 + m * 16 + lg * 4 + j) * 256 + n0 + nf * 16 + lr] = acc[m][nf][j];
}

extern "C" void kernel_launch(void* const* d_in, const int* in_sizes, int n_in,
                              void* d_out, int out_size, void* d_ws, size_t ws_size,
                              hipStream_t stream) {
    const float* x   = (const float*)d_in[0];
    const float* u   = (const float*)d_in[1];
    const float* Xm  = (const float*)d_in[2];
    const float* Um  = (const float*)d_in[3];
    const float* Y1  = (const float*)d_in[4];
    const float* XPm = (const float*)d_in[5];
    const float* B2  = (const float*)d_in[6];
    const float* D12 = (const float*)d_in[7];
    const float* bv  = (const float*)d_in[8];
    float* out = (float*)d_out;
    float* ws  = (float*)d_ws;

    float* H    = ws + WS_H;
    float* C    = ws + WS_C;
    float* CT   = ws + WS_CT;
    float* Y    = ws + WS_Y;
    float* RHS  = ws + WS_RHS;
    float* C1T  = ws + WS_C1T;
    float* D11g = ws + WS_D11;
    float* Wf   = ws + WS_WF;
    unsigned short* Bh = (unsigned short*)(ws + WS_WFH);
    unsigned short* Bm = (unsigned short*)(ws + WS_WFM);
    unsigned short* Bl = (unsigned short*)(ws + WS_WFL);
    float* wg = ws + WS_WG;

    k_build<<<656, 256, 0, stream>>>(Xm, XPm, H, C);
    k_derived<<<408, 256, 0, stream>>>(H, Um, Y1, B2, Y, RHS, C1T, D11g, Wf);
    k_m1<<<256, 256, 0, stream>>>(x, u, C1T, D12, bv, D11g, wg);
    k_chol<<<1, 256, 0, stream>>>(C);
    k_transp<<<256, 256, 0, stream>>>(C, CT);
    k_solve<<<80, 64, 0, stream>>>(C, CT, Y, RHS, Wf);
    k_packWf3<<<352, 256, 0, stream>>>(Wf, Bh, Bm, Bl);
    k_m2<<<2048, 256, 0, stream>>>(x, wg, u, Bh, Bm, Bl, out);
}